// Round 9
// baseline (33.526 us; speedup 1.0000x reference)
//
#include <hip/hip_runtime.h>
#include <math.h>

// 32 fixed taps from the problem definition (TAPS_INT), as exact fp32 values.
__device__ __constant__ float TAPS[32] = {
    -12.f,  -34.f,  -56.f,  -42.f,   18.f,  120.f,  260.f,  380.f,
    400.f,  290.f,   60.f, -210.f, -430.f, -500.f, -380.f, -120.f,
    180.f,  430.f,  540.f,  480.f,  280.f,   20.f, -220.f, -370.f,
   -400.f, -310.f, -150.f,   10.f,  120.f,  160.f,  130.f,   60.f
};

#define SCALE_INV (1.0f / 65536.0f)
#define NTH   256
#define TILE4 256                 // output float4s per block (1024 samples)
#define HALO4 8                   // left halo: 32 samples
#define NSLOT (TILE4 + HALO4)     // 264 float4 slots = 4.2 KB LDS

typedef float floatx4 __attribute__((ext_vector_type(4)));

// XOR swizzle on float4 slot index. Involution; permutes within aligned
// 64-slot (1 KB) groups; identity on the tail slots 256..263.
// Under the phase model "8 lanes sharing a bank-quad" it spreads them over
// 8 distinct quads; under "8 consecutive lanes per phase" it leaves <=2-way
// (free per m136). R4 measured stride-1 float4 LDS as ~8-way conflicted
// (13.8M cycles), so BOTH write and read sides are swizzled here.
__device__ __forceinline__ int swz(int q) { return q ^ ((q >> 3) & 7); }

__global__ __launch_bounds__(NTH)
void fir32_lds_swz(const float* __restrict__ x, float* __restrict__ y, int n) {
    __shared__ floatx4 s[NSLOT];

    const int tid = threadIdx.x;
    const long b = blockIdx.x;
    const long base4 = b * TILE4 - HALO4;   // logical f4 0 <-> global f4 base4
    const floatx4* x4 = reinterpret_cast<const floatx4*>(x);

    // ---- stage (coalesced global read, swizzled LDS write) ----
    {
        long g = base4 + tid;               // logical q = tid, lane-consecutive
        floatx4 v = {0.f, 0.f, 0.f, 0.f};
        if (g >= 0) v = x4[g];              // g < n4 always (tile layout exact)
        s[swz(tid)] = v;
        if (tid < HALO4) {                  // logical q = 256+tid (identity zone)
            s[TILE4 + tid] = x4[base4 + TILE4 + tid];  // always in-bounds
        }
    }
    __syncthreads();

    // ---- window: logical q = tid..tid+8 -> physical swz(q) ----
    float w[36];
    #pragma unroll
    for (int j = 0; j < 9; ++j) {
        floatx4 t = s[swz(tid + j)];
        w[4 * j + 0] = t.x;
        w[4 * j + 1] = t.y;
        w[4 * j + 2] = t.z;
        w[4 * j + 3] = t.w;
    }

    // Outputs 0..31 are defined as exactly 0 (block 0, threads 0..7).
    const bool head = (b == 0) && (tid < HALO4);

    float acc[4];
    #pragma unroll
    for (int j = 0; j < 4; ++j) {
        float a = 0.0f;
        #pragma unroll
        for (int k = 0; k < 32; ++k) {
            // y[4*(256b+tid) + j] needs x[m-k] == w[32 + j - k]
            a = fmaf(w[32 + j - k], TAPS[k], a);
        }
        acc[j] = head ? 0.0f : floorf(a * SCALE_INV);
    }

    // ---- one dense float4 store per thread ----
    floatx4 out = {acc[0], acc[1], acc[2], acc[3]};
    floatx4* y4 = reinterpret_cast<floatx4*>(y);
    __builtin_nontemporal_store(out, &y4[b * TILE4 + tid]);
}

extern "C" void kernel_launch(void* const* d_in, const int* in_sizes, int n_in,
                              void* d_out, int out_size, void* d_ws, size_t ws_size,
                              hipStream_t stream) {
    const float* x = (const float*)d_in[0];
    float* y = (float*)d_out;
    const int n = in_sizes[0];

    const int grid = (int)(((long)n / 4 + TILE4 - 1) / TILE4);  // 16384 blocks
    fir32_lds_swz<<<dim3(grid), dim3(NTH), 0, stream>>>(x, y, n);
}

// Round 10
// 29.454 us; speedup vs baseline: 1.1382x; 1.1382x over previous
//
#include <hip/hip_runtime.h>
#include <math.h>

// 32 fixed taps from the problem definition (TAPS_INT), as exact fp32 values.
__device__ __constant__ float TAPS[32] = {
    -12.f,  -34.f,  -56.f,  -42.f,   18.f,  120.f,  260.f,  380.f,
    400.f,  290.f,   60.f, -210.f, -430.f, -500.f, -380.f, -120.f,
    180.f,  430.f,  540.f,  480.f,  280.f,   20.f, -220.f, -370.f,
   -400.f, -310.f, -150.f,   10.f,  120.f,  160.f,  130.f,   60.f
};

#define SCALE_INV (1.0f / 65536.0f)
#define NB  2048
#define NTH 256

typedef float floatx4 __attribute__((ext_vector_type(4)));

// Issue the 10-float4 window for chunk c.
__device__ __forceinline__ void load_win(const floatx4* __restrict__ x4,
                                         long c, floatx4 v[10], bool clamp) {
    const long o4 = 2 * c;
    #pragma unroll
    for (int q = 0; q < 10; ++q) {
        long i4 = o4 - 8 + q;
        if (clamp) i4 = (i4 < 0) ? 0 : i4;  // only first-generation head chunks
        v[q] = x4[i4];
    }
}

__device__ __forceinline__ void comp_store(const floatx4 v[10], long c,
                                           floatx4* __restrict__ y4) {
    const bool head = (c < 4);              // outputs 0..31 are defined as 0
    float acc[8];
    #pragma unroll
    for (int j = 0; j < 8; ++j) {
        float a = 0.0f;
        #pragma unroll
        for (int k = 0; k < 32; ++k) {
            const int m = 32 + j - k;       // w[m] = v[m>>2][m&3]
            a = fmaf(v[m >> 2][m & 3], TAPS[k], a);
        }
        acc[j] = head ? 0.0f : floorf(a * SCALE_INV);
    }
    floatx4 o0 = {acc[0], acc[1], acc[2], acc[3]};
    floatx4 o1 = {acc[4], acc[5], acc[6], acc[7]};
    __builtin_nontemporal_store(o0, &y4[2 * c]);
    __builtin_nontemporal_store(o1, &y4[2 * c + 1]);
}

// Persistent grid-stride with cross-chunk double-buffered register prefetch:
// loads for chunk i+1 are in flight while chunk i's FMA chain runs, removing
// the per-chunk load-wait from the steady-state critical path. Ping-pong
// buffers A/B with the loop body duplicated (no register-array copies).
__global__ __launch_bounds__(NTH)
void fir32_pipe(const float* __restrict__ x, float* __restrict__ y, int n) {
    const long nchunks = (long)n >> 3;      // 8 outputs per chunk
    const long stride = (long)NB * NTH;
    long c = (long)blockIdx.x * NTH + threadIdx.x;
    if (c >= nchunks) return;

    const floatx4* x4 = reinterpret_cast<const floatx4*>(x);
    floatx4* y4 = reinterpret_cast<floatx4*>(y);

    floatx4 A[10], B[10];
    load_win(x4, c, A, true);
    while (true) {
        const long c2 = c + stride;
        const bool has2 = (c2 < nchunks);
        if (has2) load_win(x4, c2, B, false);   // prefetch: in flight during A's FMAs
        __builtin_amdgcn_sched_barrier(0);      // keep prefetch issued before compute
        comp_store(A, c, y4);
        if (!has2) return;

        const long c3 = c2 + stride;
        const bool has3 = (c3 < nchunks);
        if (has3) load_win(x4, c3, A, false);   // prefetch into A during B's FMAs
        __builtin_amdgcn_sched_barrier(0);
        comp_store(B, c2, y4);
        if (!has3) return;
        c = c3;
    }
}

extern "C" void kernel_launch(void* const* d_in, const int* in_sizes, int n_in,
                              void* d_out, int out_size, void* d_ws, size_t ws_size,
                              hipStream_t stream) {
    const float* x = (const float*)d_in[0];
    float* y = (float*)d_out;
    const int n = in_sizes[0];

    fir32_pipe<<<dim3(NB), dim3(NTH), 0, stream>>>(x, y, n);
}

// Round 11
// 29.407 us; speedup vs baseline: 1.1401x; 1.0016x over previous
//
#include <hip/hip_runtime.h>
#include <math.h>

// 32 fixed taps from the problem definition (TAPS_INT), as exact fp32 values.
__device__ __constant__ float TAPS[32] = {
    -12.f,  -34.f,  -56.f,  -42.f,   18.f,  120.f,  260.f,  380.f,
    400.f,  290.f,   60.f, -210.f, -430.f, -500.f, -380.f, -120.f,
    180.f,  430.f,  540.f,  480.f,  280.f,   20.f, -220.f, -370.f,
   -400.f, -310.f, -150.f,   10.f,  120.f,  160.f,  130.f,   60.f
};

#define SCALE_INV (1.0f / 65536.0f)

// Best measured variant (R5, 27.44 us): 8 outputs per thread, pure registers,
// no LDS. Six structural alternatives (4-out, persistent, burst-MLP,
// swizzled-LDS, ping-pong pipeline) all land 27.4-33.5 us; this is the
// memory-system floor for the 64 MB read + 67 MB write mixed stream
// (~4.9 TB/s effective vs 6.3 TB/s pure-copy ceiling).
//  - loads: 10 float4s/thread, lane stride 32B; L1 absorbs the 5x window
//    overlap (HBM fetch measured ~33 MB thanks to L3 retention).
//  - stores: 2 dense float4s/thread.
//  - uniform control flow, predicated head zeroing (outputs 0..31 == 0),
//    no early return after any store.
__global__ __launch_bounds__(256)
void fir32_dense8(const float* __restrict__ x, float* __restrict__ y, int n) {
    const int t = blockIdx.x * blockDim.x + threadIdx.x;  // 8-sample chunk id
    const long n4 = (long)n >> 2;
    const long o4 = 2L * t;                               // first output float4
    if (o4 >= n4) return;                                 // exact grid: never taken

    const float4* x4 = reinterpret_cast<const float4*>(x);
    const bool head = (t < 4);  // outputs 0..31 are defined as exactly 0

    // Window x[8t-32 .. 8t+7] = float4 indices o4-8 .. o4+1 (clamped for the
    // 4 head threads whose results are predicated to zero anyway).
    float w[40];
    #pragma unroll
    for (int c = 0; c < 10; ++c) {
        long i4 = o4 - 8 + c;
        i4 = (i4 < 0) ? 0 : i4;  // head-only clamp; loaded values unused there
        float4 v = x4[i4];
        w[4 * c + 0] = v.x;
        w[4 * c + 1] = v.y;
        w[4 * c + 2] = v.z;
        w[4 * c + 3] = v.w;
    }

    float acc[8];
    #pragma unroll
    for (int j = 0; j < 8; ++j) {
        float a = 0.0f;
        #pragma unroll
        for (int k = 0; k < 32; ++k) {
            // y[8t + j] needs x[m-k] == w[32 + j - k]
            a = fmaf(w[32 + j - k], TAPS[k], a);
        }
        acc[j] = head ? 0.0f : floorf(a * SCALE_INV);
    }

    float4* y4 = reinterpret_cast<float4*>(y);
    y4[o4]     = make_float4(acc[0], acc[1], acc[2], acc[3]);
    y4[o4 + 1] = make_float4(acc[4], acc[5], acc[6], acc[7]);
}

extern "C" void kernel_launch(void* const* d_in, const int* in_sizes, int n_in,
                              void* d_out, int out_size, void* d_ws, size_t ws_size,
                              hipStream_t stream) {
    const float* x = (const float*)d_in[0];
    float* y = (float*)d_out;
    const int n = in_sizes[0];

    const long nthreads = (long)n / 8;                   // 2^21 threads
    const int block = 256;
    const int grid = (int)((nthreads + block - 1) / block);  // 8192 blocks

    fir32_dense8<<<dim3(grid), dim3(block), 0, stream>>>(x, y, n);
}